// Round 3
// baseline (1567.957 us; speedup 1.0000x reference)
//
#include <hip/hip_runtime.h>
#include <hip/hip_bf16.h>

#define N_NODES 50000
#define E_TOTAL 800000
#define IN      128
#define HID     128
#define EPB     64
#define XOFF    ((size_t)N_NODES * HID)
#define FP      296     // fbuf pitch (ushort), 592B rows: 16B-aligned, 2-way banks
#define HP      136     // h1buf pitch, 272B rows: 16B-aligned, 2-way banks
#define CP      264     // node cat pitch

typedef __attribute__((ext_vector_type(8))) short short8v;
typedef __attribute__((ext_vector_type(4))) float f32x4;

__device__ __forceinline__ float silu_f(float x) { return x / (1.0f + __expf(-x)); }

__device__ __forceinline__ uint pkbf(float lo, float hi) {
    float2 f; f.x = lo; f.y = hi;
    __hip_bfloat162 h = __float22bfloat162_rn(f);
    union { __hip_bfloat162 h; uint u; } c; c.h = h;
    return c.u;
}

__device__ __forceinline__ ushort f2bf(float x) {
    uint u = __float_as_uint(x);
    u += 0x7fff + ((u >> 16) & 1);
    return (ushort)(u >> 16);
}

// ---------------------------------------------------------------------------
// prep: pack 5 weight matrices into MFMA fragment order (entry (kt,n,l)[j] =
// W[kt*32 + 8*(l>>4)+j][n*16 + (l&15)]) and optionally convert node_feat->bf16.
// ---------------------------------------------------------------------------
__global__ __launch_bounds__(256) void prep_kernel(
    const float* __restrict__ eW1, const float* __restrict__ eW2,
    const float* __restrict__ cW1, const float* __restrict__ nW1,
    const float* __restrict__ nW2, const float* __restrict__ node_feat,
    ushort* __restrict__ pk1, ushort* __restrict__ pk2, ushort* __restrict__ pk3,
    ushort* __restrict__ pkn1, ushort* __restrict__ pkn2,
    ushort* __restrict__ nfb, int do_nfb)
{
    int id = blockIdx.x * 256 + threadIdx.x;
    if (id < 14848) {
        const float* W; ushort* dp; int K, idx;
        if (id < 4608)       { idx = id;         W = eW1; dp = pk1;  K = 259; }
        else if (id < 6656)  { idx = id - 4608;  W = eW2; dp = pk2;  K = 128; }
        else if (id < 8704)  { idx = id - 6656;  W = cW1; dp = pk3;  K = 128; }
        else if (id < 12800) { idx = id - 8704;  W = nW1; dp = pkn1; K = 256; }
        else                 { idx = id - 12800; W = nW2; dp = pkn2; K = 128; }
        int kt = idx >> 9, n = (idx >> 6) & 7, ll = idx & 63;
        int col = (n << 4) + (ll & 15);
        short8v o;
#pragma unroll
        for (int j = 0; j < 8; ++j) {
            int k = (kt << 5) + ((ll >> 4) << 3) + j;
            o[j] = (k < K) ? (short)f2bf(W[(size_t)k * 128 + col]) : (short)0;
        }
        *reinterpret_cast<short8v*>(dp + (size_t)idx * 8) = o;
    } else if (do_nfb) {
        int idx = id - 14848;
        if (idx < N_NODES * 16) {     // 800000 rows of 8 floats
            const float4* s = reinterpret_cast<const float4*>(node_feat + (size_t)idx * 8);
            float4 a = s[0], b = s[1];
            uint4 u;
            u.x = pkbf(a.x, a.y); u.y = pkbf(a.z, a.w);
            u.z = pkbf(b.x, b.y); u.w = pkbf(b.z, b.w);
            *reinterpret_cast<uint4*>(nfb + (size_t)idx * 8) = u;
        }
    }
}

// ---------------------------------------------------------------------------
// Edge kernel: 512 thr = 8 waves, EPB=64.
// Wave w: ch=w&3 -> 32 channels (2 n-tiles), eh=w>>2 -> 32 edges (2 e-tiles).
// MFMA swapped: A=weight frag, B=feature frag -> C[row=chan(4g+r), col=edge(r16)].
// ---------------------------------------------------------------------------
template<bool NFB>
__global__ __launch_bounds__(512, 4) void edge_kernel(
    const float* __restrict__ node_feat, const ushort* __restrict__ nfb,
    const float* __restrict__ coord, const float* __restrict__ edge_feat,
    const int* __restrict__ src, const int* __restrict__ dst,
    const ushort* __restrict__ pk1, const ushort* __restrict__ pk2,
    const ushort* __restrict__ pk3,
    const float* __restrict__ eb1, const float* __restrict__ eb2,
    const float* __restrict__ cb1, const float* __restrict__ cW2,
    float* __restrict__ hacc, float* __restrict__ xacc, float* __restrict__ deg)
{
    __shared__ __attribute__((aligned(16))) ushort fbuf[EPB][FP];   // f, later msg
    __shared__ __attribute__((aligned(16))) ushort h1buf[EPB][HP];
    __shared__ int   sbuf[EPB], dbuf[EPB];
    __shared__ float xdbuf[EPB][4];
    __shared__ float pbuf[4][EPB];

    const int t   = threadIdx.x;
    const int l   = t & 63;
    const int w   = t >> 6;
    const int ch  = w & 3;
    const int eh  = w >> 2;
    const int r16 = l & 15;
    const int g   = l >> 4;
    const int e_base = blockIdx.x * EPB;

    if (t < EPB) { sbuf[t] = src[e_base + t]; dbuf[t] = dst[e_base + t]; }
    __syncthreads();

    // ---- gather f = [h_src | h_dst] ----
    {
        const int e = t >> 3;
        const int c = (t & 7) << 5;     // 0..224
        if (NFB) {
            const ushort* sp = (c < 128) ? nfb + (size_t)sbuf[e] * 128 + c
                                         : nfb + (size_t)dbuf[e] * 128 + (c - 128);
            const short8v* spv = reinterpret_cast<const short8v*>(sp);
#pragma unroll
            for (int i = 0; i < 4; ++i)
                *reinterpret_cast<short8v*>(&fbuf[e][c + (i << 3)]) = spv[i];
        } else {
            const float* sp = (c < 128) ? node_feat + (size_t)sbuf[e] * 128 + c
                                        : node_feat + (size_t)dbuf[e] * 128 + (c - 128);
            const float4* spv = reinterpret_cast<const float4*>(sp);
#pragma unroll
            for (int i = 0; i < 4; ++i) {
                float4 a = spv[2 * i], b = spv[2 * i + 1];
                uint4 u;
                u.x = pkbf(a.x, a.y); u.y = pkbf(a.z, a.w);
                u.z = pkbf(b.x, b.y); u.w = pkbf(b.z, b.w);
                *reinterpret_cast<uint4*>(&fbuf[e][c + (i << 3)]) = u;
            }
        }
    }
    if (t < EPB) {
        const int e = t, s = sbuf[e], d = dbuf[e];
        float dx = coord[(size_t)s*3+0] - coord[(size_t)d*3+0];
        float dy = coord[(size_t)s*3+1] - coord[(size_t)d*3+1];
        float dz = coord[(size_t)s*3+2] - coord[(size_t)d*3+2];
        float radial = dx*dx + dy*dy + dz*dz;
        float inv = 1.0f / (sqrtf(radial) + 1e-30f);
        fbuf[e][256] = f2bf(radial);
        fbuf[e][257] = f2bf(edge_feat[(size_t)(e_base + e)*2 + 0]);
        fbuf[e][258] = f2bf(edge_feat[(size_t)(e_base + e)*2 + 1]);
#pragma unroll
        for (int k = 259; k < 288; ++k) fbuf[e][k] = 0;
        xdbuf[e][0] = dx * inv; xdbuf[e][1] = dy * inv; xdbuf[e][2] = dz * inv;
    }
    __syncthreads();

    const f32x4 zero = {0.f, 0.f, 0.f, 0.f};
    const short8v* pkv1 = reinterpret_cast<const short8v*>(pk1);
    const short8v* pkv2 = reinterpret_cast<const short8v*>(pk2);
    const short8v* pkv3 = reinterpret_cast<const short8v*>(pk3);

    // ---- GEMM1: K=288 ----
    f32x4 acc[2][2];
    acc[0][0] = zero; acc[0][1] = zero; acc[1][0] = zero; acc[1][1] = zero;
    for (int kt = 0; kt < 9; ++kt) {
        short8v b0 = *reinterpret_cast<const short8v*>(&fbuf[(eh << 5) + r16][(kt << 5) + (g << 3)]);
        short8v b1 = *reinterpret_cast<const short8v*>(&fbuf[(eh << 5) + 16 + r16][(kt << 5) + (g << 3)]);
#pragma unroll
        for (int nt = 0; nt < 2; ++nt) {
            short8v a = pkv1[(((kt << 3) + (ch << 1) + nt) << 6) + l];
            acc[0][nt] = __builtin_amdgcn_mfma_f32_16x16x32_bf16(a, b0, acc[0][nt], 0, 0, 0);
            acc[1][nt] = __builtin_amdgcn_mfma_f32_16x16x32_bf16(a, b1, acc[1][nt], 0, 0, 0);
        }
    }
#pragma unroll
    for (int nt = 0; nt < 2; ++nt) {
        int cb = (ch << 5) + (nt << 4) + (g << 2);
        float4 bias = *reinterpret_cast<const float4*>(&eb1[cb]);
#pragma unroll
        for (int et = 0; et < 2; ++et) {
            int e = (eh << 5) + (et << 4) + r16;
            f32x4 v = acc[et][nt];
            uint2 p;
            p.x = pkbf(silu_f(v[0] + bias.x), silu_f(v[1] + bias.y));
            p.y = pkbf(silu_f(v[2] + bias.z), silu_f(v[3] + bias.w));
            *reinterpret_cast<uint2*>(&h1buf[e][cb]) = p;
        }
    }
    __syncthreads();

    // ---- GEMM2: K=128, msg kept in regs + written to fbuf ----
    acc[0][0] = zero; acc[0][1] = zero; acc[1][0] = zero; acc[1][1] = zero;
    for (int kt = 0; kt < 4; ++kt) {
        short8v b0 = *reinterpret_cast<const short8v*>(&h1buf[(eh << 5) + r16][(kt << 5) + (g << 3)]);
        short8v b1 = *reinterpret_cast<const short8v*>(&h1buf[(eh << 5) + 16 + r16][(kt << 5) + (g << 3)]);
#pragma unroll
        for (int nt = 0; nt < 2; ++nt) {
            short8v a = pkv2[(((kt << 3) + (ch << 1) + nt) << 6) + l];
            acc[0][nt] = __builtin_amdgcn_mfma_f32_16x16x32_bf16(a, b0, acc[0][nt], 0, 0, 0);
            acc[1][nt] = __builtin_amdgcn_mfma_f32_16x16x32_bf16(a, b1, acc[1][nt], 0, 0, 0);
        }
    }
    float msg[2][2][4];
#pragma unroll
    for (int nt = 0; nt < 2; ++nt) {
        int cb = (ch << 5) + (nt << 4) + (g << 2);
        float4 bias = *reinterpret_cast<const float4*>(&eb2[cb]);
#pragma unroll
        for (int et = 0; et < 2; ++et) {
            int e = (eh << 5) + (et << 4) + r16;
            f32x4 v = acc[et][nt];
            float m0 = silu_f(v[0] + bias.x), m1 = silu_f(v[1] + bias.y);
            float m2 = silu_f(v[2] + bias.z), m3 = silu_f(v[3] + bias.w);
            msg[et][nt][0] = m0; msg[et][nt][1] = m1;
            msg[et][nt][2] = m2; msg[et][nt][3] = m3;
            uint2 p; p.x = pkbf(m0, m1); p.y = pkbf(m2, m3);
            *reinterpret_cast<uint2*>(&fbuf[e][cb]) = p;
        }
    }
    __syncthreads();

    // ---- scatter msg_h (overlaps GEMM3) ----
#pragma unroll
    for (int et = 0; et < 2; ++et) {
        int gd = dbuf[(eh << 5) + (et << 4) + r16];
#pragma unroll
        for (int nt = 0; nt < 2; ++nt) {
            int cb = (ch << 5) + (nt << 4) + (g << 2);
            float* dp = hacc + (size_t)gd * HID + cb;
            atomicAdd(&dp[0], msg[et][nt][0]);
            atomicAdd(&dp[1], msg[et][nt][1]);
            atomicAdd(&dp[2], msg[et][nt][2]);
            atomicAdd(&dp[3], msg[et][nt][3]);
        }
    }

    // ---- GEMM3: K=128 -> silu -> dot cW2 ----
    acc[0][0] = zero; acc[0][1] = zero; acc[1][0] = zero; acc[1][1] = zero;
    for (int kt = 0; kt < 4; ++kt) {
        short8v b0 = *reinterpret_cast<const short8v*>(&fbuf[(eh << 5) + r16][(kt << 5) + (g << 3)]);
        short8v b1 = *reinterpret_cast<const short8v*>(&fbuf[(eh << 5) + 16 + r16][(kt << 5) + (g << 3)]);
#pragma unroll
        for (int nt = 0; nt < 2; ++nt) {
            short8v a = pkv3[(((kt << 3) + (ch << 1) + nt) << 6) + l];
            acc[0][nt] = __builtin_amdgcn_mfma_f32_16x16x32_bf16(a, b0, acc[0][nt], 0, 0, 0);
            acc[1][nt] = __builtin_amdgcn_mfma_f32_16x16x32_bf16(a, b1, acc[1][nt], 0, 0, 0);
        }
    }
    float part[2] = {0.f, 0.f};
#pragma unroll
    for (int nt = 0; nt < 2; ++nt) {
        int cb = (ch << 5) + (nt << 4) + (g << 2);
        float4 bias = *reinterpret_cast<const float4*>(&cb1[cb]);
        float4 cw   = *reinterpret_cast<const float4*>(&cW2[cb]);
#pragma unroll
        for (int et = 0; et < 2; ++et) {
            f32x4 v = acc[et][nt];
            part[et] += silu_f(v[0] + bias.x) * cw.x + silu_f(v[1] + bias.y) * cw.y
                      + silu_f(v[2] + bias.z) * cw.z + silu_f(v[3] + bias.w) * cw.w;
        }
    }
#pragma unroll
    for (int et = 0; et < 2; ++et) {
        part[et] += __shfl_xor(part[et], 16);
        part[et] += __shfl_xor(part[et], 32);
    }
    if (l < 16) {
        pbuf[ch][(eh << 5) + r16]      = part[0];
        pbuf[ch][(eh << 5) + 16 + r16] = part[1];
    }
    __syncthreads();

    if (t < EPB) {
        float s = pbuf[0][t] + pbuf[1][t] + pbuf[2][t] + pbuf[3][t];
        int gd = dbuf[t];
        atomicAdd(&xacc[(size_t)gd*3 + 0], s * xdbuf[t][0]);
        atomicAdd(&xacc[(size_t)gd*3 + 1], s * xdbuf[t][1]);
        atomicAdd(&xacc[(size_t)gd*3 + 2], s * xdbuf[t][2]);
        atomicAdd(&deg[gd], 1.0f);
    }
}

// ---------------------------------------------------------------------------
// Node kernel (MFMA): 256 thr = 4 waves, 32 nodes/block.
// Wave w: ch=w&1 -> 64 channels (4 n-tiles), eh=w>>1 -> 16 nodes.
// ---------------------------------------------------------------------------
template<bool NFB>
__global__ __launch_bounds__(256) void node_kernel(
    const float* __restrict__ node_feat, const ushort* __restrict__ nfb,
    const float* __restrict__ coord,
    const ushort* __restrict__ pkn1, const ushort* __restrict__ pkn2,
    const float* __restrict__ nb1, const float* __restrict__ nb2,
    float* __restrict__ dout, const float* __restrict__ deg)
{
    __shared__ __attribute__((aligned(16))) ushort catb[32][CP];
    __shared__ __attribute__((aligned(16))) ushort h1b[32][HP];

    const int t   = threadIdx.x;
    const int l   = t & 63;
    const int w   = t >> 6;
    const int ch  = w & 1;
    const int eh  = w >> 1;
    const int r16 = l & 15;
    const int g   = l >> 4;
    const int nb  = blockIdx.x * 32;

    // gather cat = [node_feat | h_neigh]
    {
        int nd = t >> 3;
        int c  = (t & 7) << 5;
        int gn = nb + nd; if (gn >= N_NODES) gn = N_NODES - 1;
        if (c < 128) {
            if (NFB) {
                const short8v* spv = reinterpret_cast<const short8v*>(nfb + (size_t)gn * 128 + c);
#pragma unroll
                for (int i = 0; i < 4; ++i)
                    *reinterpret_cast<short8v*>(&catb[nd][c + (i << 3)]) = spv[i];
            } else {
                const float4* spv = reinterpret_cast<const float4*>(node_feat + (size_t)gn * 128 + c);
#pragma unroll
                for (int i = 0; i < 4; ++i) {
                    float4 a = spv[2 * i], b = spv[2 * i + 1];
                    uint4 u;
                    u.x = pkbf(a.x, a.y); u.y = pkbf(a.z, a.w);
                    u.z = pkbf(b.x, b.y); u.w = pkbf(b.z, b.w);
                    *reinterpret_cast<uint4*>(&catb[nd][c + (i << 3)]) = u;
                }
            }
        } else {
            const float4* spv = reinterpret_cast<const float4*>(dout + (size_t)gn * HID + (c - 128));
#pragma unroll
            for (int i = 0; i < 4; ++i) {
                float4 a = spv[2 * i], b = spv[2 * i + 1];
                uint4 u;
                u.x = pkbf(a.x, a.y); u.y = pkbf(a.z, a.w);
                u.z = pkbf(b.x, b.y); u.w = pkbf(b.z, b.w);
                *reinterpret_cast<uint4*>(&catb[nd][c + (i << 3)]) = u;
            }
        }
    }
    __syncthreads();

    const f32x4 zero = {0.f, 0.f, 0.f, 0.f};
    const short8v* pv1 = reinterpret_cast<const short8v*>(pkn1);
    const short8v* pv2 = reinterpret_cast<const short8v*>(pkn2);

    // GEMM1: K=256
    f32x4 acc[4];
#pragma unroll
    for (int nt = 0; nt < 4; ++nt) acc[nt] = zero;
    for (int kt = 0; kt < 8; ++kt) {
        short8v b = *reinterpret_cast<const short8v*>(&catb[(eh << 4) + r16][(kt << 5) + (g << 3)]);
#pragma unroll
        for (int nt = 0; nt < 4; ++nt) {
            short8v a = pv1[(((kt << 3) + (ch << 2) + nt) << 6) + l];
            acc[nt] = __builtin_amdgcn_mfma_f32_16x16x32_bf16(a, b, acc[nt], 0, 0, 0);
        }
    }
#pragma unroll
    for (int nt = 0; nt < 4; ++nt) {
        int cb = (ch << 6) + (nt << 4) + (g << 2);
        float4 bias = *reinterpret_cast<const float4*>(&nb1[cb]);
        int nd = (eh << 4) + r16;
        f32x4 v = acc[nt];
        uint2 p;
        p.x = pkbf(silu_f(v[0] + bias.x), silu_f(v[1] + bias.y));
        p.y = pkbf(silu_f(v[2] + bias.z), silu_f(v[3] + bias.w));
        *reinterpret_cast<uint2*>(&h1b[nd][cb]) = p;
    }
    __syncthreads();

    // GEMM2: K=128 -> write h out
#pragma unroll
    for (int nt = 0; nt < 4; ++nt) acc[nt] = zero;
    for (int kt = 0; kt < 4; ++kt) {
        short8v b = *reinterpret_cast<const short8v*>(&h1b[(eh << 4) + r16][(kt << 5) + (g << 3)]);
#pragma unroll
        for (int nt = 0; nt < 4; ++nt) {
            short8v a = pv2[(((kt << 3) + (ch << 2) + nt) << 6) + l];
            acc[nt] = __builtin_amdgcn_mfma_f32_16x16x32_bf16(a, b, acc[nt], 0, 0, 0);
        }
    }
    {
        int gw = nb + (eh << 4) + r16;
        if (gw < N_NODES) {
#pragma unroll
            for (int nt = 0; nt < 4; ++nt) {
                int cb = (ch << 6) + (nt << 4) + (g << 2);
                float4 bias = *reinterpret_cast<const float4*>(&nb2[cb]);
                f32x4 v = acc[nt];
                float4 o;
                o.x = v[0] + bias.x; o.y = v[1] + bias.y;
                o.z = v[2] + bias.z; o.w = v[3] + bias.w;
                *reinterpret_cast<float4*>(&dout[(size_t)gw * HID + cb]) = o;
            }
        }
    }

    // x update
    if (t < 96) {
        int nd = t / 3, d = t - 3 * nd;
        int gn = nb + nd;
        if (gn < N_NODES) {
            size_t xi = XOFF + (size_t)gn * 3 + d;
            float dg = deg[gn];
            dg = dg > 1.0f ? dg : 1.0f;
            dout[xi] = coord[(size_t)gn * 3 + d] + dout[xi] / dg;
        }
    }
}

extern "C" void kernel_launch(void* const* d_in, const int* in_sizes, int n_in,
                              void* d_out, int out_size, void* d_ws, size_t ws_size,
                              hipStream_t stream) {
    const float* node_feat = (const float*)d_in[0];
    const float* coord     = (const float*)d_in[1];
    const float* edge_feat = (const float*)d_in[2];
    const int*   src       = (const int*)d_in[3];
    const int*   dst       = (const int*)d_in[4];
    const float* eW1 = (const float*)d_in[5];
    const float* eb1 = (const float*)d_in[6];
    const float* eW2 = (const float*)d_in[7];
    const float* eb2 = (const float*)d_in[8];
    const float* nW1 = (const float*)d_in[9];
    const float* nb1 = (const float*)d_in[10];
    const float* nW2 = (const float*)d_in[11];
    const float* nb2 = (const float*)d_in[12];
    const float* cW1 = (const float*)d_in[13];
    const float* cb1 = (const float*)d_in[14];
    const float* cW2 = (const float*)d_in[15];

    float* out = (float*)d_out;
    float* deg = (float*)d_ws;
    // ws layout (bytes): deg 0..200000 | pk1 73728 | pk2 32768 | pk3 32768
    //                    | pkn1 65536 | pkn2 32768 | nfb 12800000
    char* base = (char*)d_ws;
    ushort* pk1  = (ushort*)(base + 200000);
    ushort* pk2  = (ushort*)(base + 273728);
    ushort* pk3  = (ushort*)(base + 306496);
    ushort* pkn1 = (ushort*)(base + 339264);
    ushort* pkn2 = (ushort*)(base + 404800);
    ushort* nfb  = (ushort*)(base + 437568);
    const size_t need_nfb = 437568 + (size_t)N_NODES * 128 * 2;
    const bool use_nfb = ws_size >= need_nfb;

    hipMemsetAsync(d_out, 0, (size_t)out_size * sizeof(float), stream);
    hipMemsetAsync(d_ws, 0, 200000, stream);

    int prep_grid = use_nfb ? (14848 + N_NODES * 16 + 255) / 256 : 58;
    prep_kernel<<<prep_grid, 256, 0, stream>>>(
        eW1, eW2, cW1, nW1, nW2, node_feat,
        pk1, pk2, pk3, pkn1, pkn2, nfb, use_nfb ? 1 : 0);

    if (use_nfb) {
        edge_kernel<true><<<E_TOTAL / EPB, 512, 0, stream>>>(
            node_feat, nfb, coord, edge_feat, src, dst,
            pk1, pk2, pk3, eb1, eb2, cb1, cW2, out, out + XOFF, deg);
        node_kernel<true><<<(N_NODES + 31) / 32, 256, 0, stream>>>(
            node_feat, nfb, coord, pkn1, pkn2, nb1, nb2, out, deg);
    } else {
        edge_kernel<false><<<E_TOTAL / EPB, 512, 0, stream>>>(
            node_feat, nfb, coord, edge_feat, src, dst,
            pk1, pk2, pk3, eb1, eb2, cb1, cW2, out, out + XOFF, deg);
        node_kernel<false><<<(N_NODES + 31) / 32, 256, 0, stream>>>(
            node_feat, nfb, coord, pkn1, pkn2, nb1, nb2, out, deg);
    }
}

// Round 4
// 554.953 us; speedup vs baseline: 2.8254x; 2.8254x over previous
//
#include <hip/hip_runtime.h>
#include <hip/hip_bf16.h>

#define N_NODES 50000
#define E_TOTAL 800000
#define IN      128
#define HID     128
#define EPB     64
#define XOFF    ((size_t)N_NODES * HID)
#define FP      296     // fbuf pitch (ushort), 592B rows: 16B-aligned
#define HP      136     // h1buf pitch, 272B rows: 16B-aligned
#define CP      264     // node cat pitch

typedef __attribute__((ext_vector_type(8))) short short8v;
typedef __attribute__((ext_vector_type(4))) float f32x4;

__device__ __forceinline__ float silu_f(float x) { return x / (1.0f + __expf(-x)); }

__device__ __forceinline__ uint pkbf(float lo, float hi) {
    float2 f; f.x = lo; f.y = hi;
    __hip_bfloat162 h = __float22bfloat162_rn(f);
    union { __hip_bfloat162 h; uint u; } c; c.h = h;
    return c.u;
}

__device__ __forceinline__ ushort f2bf(float x) {
    uint u = __float_as_uint(x);
    u += 0x7fff + ((u >> 16) & 1);
    return (ushort)(u >> 16);
}

// ---------------------------------------------------------------------------
// prep: pack 5 weight matrices into MFMA fragment order (entry (kt,n,l)[j] =
// W[kt*32 + 8*(l>>4)+j][n*16 + (l&15)]) and convert node_feat->bf16.
// ---------------------------------------------------------------------------
__global__ __launch_bounds__(256) void prep_kernel(
    const float* __restrict__ eW1, const float* __restrict__ eW2,
    const float* __restrict__ cW1, const float* __restrict__ nW1,
    const float* __restrict__ nW2, const float* __restrict__ node_feat,
    ushort* __restrict__ pk1, ushort* __restrict__ pk2, ushort* __restrict__ pk3,
    ushort* __restrict__ pkn1, ushort* __restrict__ pkn2,
    ushort* __restrict__ nfb, int do_nfb)
{
    int id = blockIdx.x * 256 + threadIdx.x;
    if (id < 14848) {
        const float* W; ushort* dp; int K, idx;
        if (id < 4608)       { idx = id;         W = eW1; dp = pk1;  K = 259; }
        else if (id < 6656)  { idx = id - 4608;  W = eW2; dp = pk2;  K = 128; }
        else if (id < 8704)  { idx = id - 6656;  W = cW1; dp = pk3;  K = 128; }
        else if (id < 12800) { idx = id - 8704;  W = nW1; dp = pkn1; K = 256; }
        else                 { idx = id - 12800; W = nW2; dp = pkn2; K = 128; }
        int kt = idx >> 9, n = (idx >> 6) & 7, ll = idx & 63;
        int col = (n << 4) + (ll & 15);
        short8v o;
#pragma unroll
        for (int j = 0; j < 8; ++j) {
            int k = (kt << 5) + ((ll >> 4) << 3) + j;
            o[j] = (k < K) ? (short)f2bf(W[(size_t)k * 128 + col]) : (short)0;
        }
        *reinterpret_cast<short8v*>(dp + (size_t)idx * 8) = o;
    } else if (do_nfb) {
        int idx = id - 14848;
        if (idx < N_NODES * 16) {
            const float4* s = reinterpret_cast<const float4*>(node_feat + (size_t)idx * 8);
            float4 a = s[0], b = s[1];
            uint4 u;
            u.x = pkbf(a.x, a.y); u.y = pkbf(a.z, a.w);
            u.z = pkbf(b.x, b.y); u.w = pkbf(b.z, b.w);
            *reinterpret_cast<uint4*>(nfb + (size_t)idx * 8) = u;
        }
    }
}

// ---------------------------------------------------------------------------
// Edge kernel: 512 thr = 8 waves, EPB=64.
// Wave w: ch=w&3 -> 32 channels (2 n-tiles), eh=w>>2 -> 32 edges (2 e-tiles).
// MFMA swapped: A=weight frag, B=feature frag -> C[row=chan, col=edge].
// h-scatter re-coalesced through LDS (msg lives in fbuf as [edge][chan]).
// ---------------------------------------------------------------------------
template<bool NFB>
__global__ __launch_bounds__(512, 4) void edge_kernel(
    const float* __restrict__ node_feat, const ushort* __restrict__ nfb,
    const float* __restrict__ coord, const float* __restrict__ edge_feat,
    const int* __restrict__ src, const int* __restrict__ dst,
    const ushort* __restrict__ pk1, const ushort* __restrict__ pk2,
    const ushort* __restrict__ pk3,
    const float* __restrict__ eb1, const float* __restrict__ eb2,
    const float* __restrict__ cb1, const float* __restrict__ cW2,
    float* __restrict__ hacc, float* __restrict__ xacc, float* __restrict__ deg)
{
    __shared__ __attribute__((aligned(16))) ushort fbuf[EPB][FP];   // f, later msg
    __shared__ __attribute__((aligned(16))) ushort h1buf[EPB][HP];
    __shared__ int   sbuf[EPB], dbuf[EPB];
    __shared__ float xdbuf[EPB][4];
    __shared__ float pbuf[4][EPB];

    const int t   = threadIdx.x;
    const int l   = t & 63;
    const int w   = t >> 6;
    const int ch  = w & 3;
    const int eh  = w >> 2;
    const int r16 = l & 15;
    const int g   = l >> 4;
    const int e_base = blockIdx.x * EPB;

    if (t < EPB) { sbuf[t] = src[e_base + t]; dbuf[t] = dst[e_base + t]; }
    __syncthreads();

    // ---- gather f = [h_src | h_dst] ----
    {
        const int e = t >> 3;
        const int c = (t & 7) << 5;     // 0..224
        if (NFB) {
            const ushort* sp = (c < 128) ? nfb + (size_t)sbuf[e] * 128 + c
                                         : nfb + (size_t)dbuf[e] * 128 + (c - 128);
            const short8v* spv = reinterpret_cast<const short8v*>(sp);
#pragma unroll
            for (int i = 0; i < 4; ++i)
                *reinterpret_cast<short8v*>(&fbuf[e][c + (i << 3)]) = spv[i];
        } else {
            const float* sp = (c < 128) ? node_feat + (size_t)sbuf[e] * 128 + c
                                        : node_feat + (size_t)dbuf[e] * 128 + (c - 128);
            const float4* spv = reinterpret_cast<const float4*>(sp);
#pragma unroll
            for (int i = 0; i < 4; ++i) {
                float4 a = spv[2 * i], b = spv[2 * i + 1];
                uint4 u;
                u.x = pkbf(a.x, a.y); u.y = pkbf(a.z, a.w);
                u.z = pkbf(b.x, b.y); u.w = pkbf(b.z, b.w);
                *reinterpret_cast<uint4*>(&fbuf[e][c + (i << 3)]) = u;
            }
        }
    }
    if (t < EPB) {
        const int e = t, s = sbuf[e], d = dbuf[e];
        float dx = coord[(size_t)s*3+0] - coord[(size_t)d*3+0];
        float dy = coord[(size_t)s*3+1] - coord[(size_t)d*3+1];
        float dz = coord[(size_t)s*3+2] - coord[(size_t)d*3+2];
        float radial = dx*dx + dy*dy + dz*dz;
        float inv = 1.0f / (sqrtf(radial) + 1e-30f);
        fbuf[e][256] = f2bf(radial);
        fbuf[e][257] = f2bf(edge_feat[(size_t)(e_base + e)*2 + 0]);
        fbuf[e][258] = f2bf(edge_feat[(size_t)(e_base + e)*2 + 1]);
#pragma unroll
        for (int k = 259; k < 288; ++k) fbuf[e][k] = 0;
        xdbuf[e][0] = dx * inv; xdbuf[e][1] = dy * inv; xdbuf[e][2] = dz * inv;
    }
    __syncthreads();

    const f32x4 zero = {0.f, 0.f, 0.f, 0.f};
    const short8v* pkv1 = reinterpret_cast<const short8v*>(pk1);
    const short8v* pkv2 = reinterpret_cast<const short8v*>(pk2);
    const short8v* pkv3 = reinterpret_cast<const short8v*>(pk3);

    // ---- GEMM1: K=288 ----
    f32x4 acc[2][2];
    acc[0][0] = zero; acc[0][1] = zero; acc[1][0] = zero; acc[1][1] = zero;
    for (int kt = 0; kt < 9; ++kt) {
        short8v b0 = *reinterpret_cast<const short8v*>(&fbuf[(eh << 5) + r16][(kt << 5) + (g << 3)]);
        short8v b1 = *reinterpret_cast<const short8v*>(&fbuf[(eh << 5) + 16 + r16][(kt << 5) + (g << 3)]);
#pragma unroll
        for (int nt = 0; nt < 2; ++nt) {
            short8v a = pkv1[(((kt << 3) + (ch << 1) + nt) << 6) + l];
            acc[0][nt] = __builtin_amdgcn_mfma_f32_16x16x32_bf16(a, b0, acc[0][nt], 0, 0, 0);
            acc[1][nt] = __builtin_amdgcn_mfma_f32_16x16x32_bf16(a, b1, acc[1][nt], 0, 0, 0);
        }
    }
#pragma unroll
    for (int nt = 0; nt < 2; ++nt) {
        int cb = (ch << 5) + (nt << 4) + (g << 2);
        float4 bias = *reinterpret_cast<const float4*>(&eb1[cb]);
#pragma unroll
        for (int et = 0; et < 2; ++et) {
            int e = (eh << 5) + (et << 4) + r16;
            f32x4 v = acc[et][nt];
            uint2 p;
            p.x = pkbf(silu_f(v[0] + bias.x), silu_f(v[1] + bias.y));
            p.y = pkbf(silu_f(v[2] + bias.z), silu_f(v[3] + bias.w));
            *reinterpret_cast<uint2*>(&h1buf[e][cb]) = p;
        }
    }
    __syncthreads();

    // ---- GEMM2: K=128 -> silu -> msg (bf16, [edge][chan] in fbuf) ----
    acc[0][0] = zero; acc[0][1] = zero; acc[1][0] = zero; acc[1][1] = zero;
    for (int kt = 0; kt < 4; ++kt) {
        short8v b0 = *reinterpret_cast<const short8v*>(&h1buf[(eh << 5) + r16][(kt << 5) + (g << 3)]);
        short8v b1 = *reinterpret_cast<const short8v*>(&h1buf[(eh << 5) + 16 + r16][(kt << 5) + (g << 3)]);
#pragma unroll
        for (int nt = 0; nt < 2; ++nt) {
            short8v a = pkv2[(((kt << 3) + (ch << 1) + nt) << 6) + l];
            acc[0][nt] = __builtin_amdgcn_mfma_f32_16x16x32_bf16(a, b0, acc[0][nt], 0, 0, 0);
            acc[1][nt] = __builtin_amdgcn_mfma_f32_16x16x32_bf16(a, b1, acc[1][nt], 0, 0, 0);
        }
    }
#pragma unroll
    for (int nt = 0; nt < 2; ++nt) {
        int cb = (ch << 5) + (nt << 4) + (g << 2);
        float4 bias = *reinterpret_cast<const float4*>(&eb2[cb]);
#pragma unroll
        for (int et = 0; et < 2; ++et) {
            int e = (eh << 5) + (et << 4) + r16;
            f32x4 v = acc[et][nt];
            uint2 p;
            p.x = pkbf(silu_f(v[0] + bias.x), silu_f(v[1] + bias.y));
            p.y = pkbf(silu_f(v[2] + bias.z), silu_f(v[3] + bias.w));
            *reinterpret_cast<uint2*>(&fbuf[e][cb]) = p;
        }
    }
    __syncthreads();

    // ---- scatter msg_h from LDS, coalesced: 16 lanes = one 64B line ----
    {
        const int se = t >> 4;            // 0..31
        const int sc = t & 15;
#pragma unroll
        for (int p = 0; p < 2; ++p) {
            int e = se + (p << 5);
            int gd = dbuf[e];
            float* dp = hacc + (size_t)gd * HID + sc;
#pragma unroll
            for (int i = 0; i < 8; ++i) {
                ushort us = fbuf[e][sc + (i << 4)];
                atomicAdd(dp + (i << 4), __uint_as_float((uint)us << 16));
            }
        }
    }

    // ---- GEMM3: K=128 -> silu -> dot cW2 ----
    acc[0][0] = zero; acc[0][1] = zero; acc[1][0] = zero; acc[1][1] = zero;
    for (int kt = 0; kt < 4; ++kt) {
        short8v b0 = *reinterpret_cast<const short8v*>(&fbuf[(eh << 5) + r16][(kt << 5) + (g << 3)]);
        short8v b1 = *reinterpret_cast<const short8v*>(&fbuf[(eh << 5) + 16 + r16][(kt << 5) + (g << 3)]);
#pragma unroll
        for (int nt = 0; nt < 2; ++nt) {
            short8v a = pkv3[(((kt << 3) + (ch << 1) + nt) << 6) + l];
            acc[0][nt] = __builtin_amdgcn_mfma_f32_16x16x32_bf16(a, b0, acc[0][nt], 0, 0, 0);
            acc[1][nt] = __builtin_amdgcn_mfma_f32_16x16x32_bf16(a, b1, acc[1][nt], 0, 0, 0);
        }
    }
    float part[2] = {0.f, 0.f};
#pragma unroll
    for (int nt = 0; nt < 2; ++nt) {
        int cb = (ch << 5) + (nt << 4) + (g << 2);
        float4 bias = *reinterpret_cast<const float4*>(&cb1[cb]);
        float4 cw   = *reinterpret_cast<const float4*>(&cW2[cb]);
#pragma unroll
        for (int et = 0; et < 2; ++et) {
            f32x4 v = acc[et][nt];
            part[et] += silu_f(v[0] + bias.x) * cw.x + silu_f(v[1] + bias.y) * cw.y
                      + silu_f(v[2] + bias.z) * cw.z + silu_f(v[3] + bias.w) * cw.w;
        }
    }
#pragma unroll
    for (int et = 0; et < 2; ++et) {
        part[et] += __shfl_xor(part[et], 16);
        part[et] += __shfl_xor(part[et], 32);
    }
    if (l < 16) {
        pbuf[ch][(eh << 5) + r16]      = part[0];
        pbuf[ch][(eh << 5) + 16 + r16] = part[1];
    }
    __syncthreads();

    if (t < EPB) {
        float s = pbuf[0][t] + pbuf[1][t] + pbuf[2][t] + pbuf[3][t];
        int gd = dbuf[t];
        atomicAdd(&xacc[(size_t)gd*3 + 0], s * xdbuf[t][0]);
        atomicAdd(&xacc[(size_t)gd*3 + 1], s * xdbuf[t][1]);
        atomicAdd(&xacc[(size_t)gd*3 + 2], s * xdbuf[t][2]);
        atomicAdd(&deg[gd], 1.0f);
    }
}

// ---------------------------------------------------------------------------
// Node kernel (MFMA): 256 thr = 4 waves, 32 nodes/block.
// ---------------------------------------------------------------------------
template<bool NFB>
__global__ __launch_bounds__(256) void node_kernel(
    const float* __restrict__ node_feat, const ushort* __restrict__ nfb,
    const float* __restrict__ coord,
    const ushort* __restrict__ pkn1, const ushort* __restrict__ pkn2,
    const float* __restrict__ nb1, const float* __restrict__ nb2,
    float* __restrict__ dout, const float* __restrict__ deg)
{
    __shared__ __attribute__((aligned(16))) ushort catb[32][CP];
    __shared__ __attribute__((aligned(16))) ushort h1b[32][HP];

    const int t   = threadIdx.x;
    const int l   = t & 63;
    const int w   = t >> 6;
    const int ch  = w & 1;
    const int eh  = w >> 1;
    const int r16 = l & 15;
    const int g   = l >> 4;
    const int nb  = blockIdx.x * 32;

    {
        int nd = t >> 3;
        int c  = (t & 7) << 5;
        int gn = nb + nd; if (gn >= N_NODES) gn = N_NODES - 1;
        if (c < 128) {
            if (NFB) {
                const short8v* spv = reinterpret_cast<const short8v*>(nfb + (size_t)gn * 128 + c);
#pragma unroll
                for (int i = 0; i < 4; ++i)
                    *reinterpret_cast<short8v*>(&catb[nd][c + (i << 3)]) = spv[i];
            } else {
                const float4* spv = reinterpret_cast<const float4*>(node_feat + (size_t)gn * 128 + c);
#pragma unroll
                for (int i = 0; i < 4; ++i) {
                    float4 a = spv[2 * i], b = spv[2 * i + 1];
                    uint4 u;
                    u.x = pkbf(a.x, a.y); u.y = pkbf(a.z, a.w);
                    u.z = pkbf(b.x, b.y); u.w = pkbf(b.z, b.w);
                    *reinterpret_cast<uint4*>(&catb[nd][c + (i << 3)]) = u;
                }
            }
        } else {
            const float4* spv = reinterpret_cast<const float4*>(dout + (size_t)gn * HID + (c - 128));
#pragma unroll
            for (int i = 0; i < 4; ++i) {
                float4 a = spv[2 * i], b = spv[2 * i + 1];
                uint4 u;
                u.x = pkbf(a.x, a.y); u.y = pkbf(a.z, a.w);
                u.z = pkbf(b.x, b.y); u.w = pkbf(b.z, b.w);
                *reinterpret_cast<uint4*>(&catb[nd][c + (i << 3)]) = u;
            }
        }
    }
    __syncthreads();

    const f32x4 zero = {0.f, 0.f, 0.f, 0.f};
    const short8v* pv1 = reinterpret_cast<const short8v*>(pkn1);
    const short8v* pv2 = reinterpret_cast<const short8v*>(pkn2);

    f32x4 acc[4];
#pragma unroll
    for (int nt = 0; nt < 4; ++nt) acc[nt] = zero;
    for (int kt = 0; kt < 8; ++kt) {
        short8v b = *reinterpret_cast<const short8v*>(&catb[(eh << 4) + r16][(kt << 5) + (g << 3)]);
#pragma unroll
        for (int nt = 0; nt < 4; ++nt) {
            short8v a = pv1[(((kt << 3) + (ch << 2) + nt) << 6) + l];
            acc[nt] = __builtin_amdgcn_mfma_f32_16x16x32_bf16(a, b, acc[nt], 0, 0, 0);
        }
    }
#pragma unroll
    for (int nt = 0; nt < 4; ++nt) {
        int cb = (ch << 6) + (nt << 4) + (g << 2);
        float4 bias = *reinterpret_cast<const float4*>(&nb1[cb]);
        int nd = (eh << 4) + r16;
        f32x4 v = acc[nt];
        uint2 p;
        p.x = pkbf(silu_f(v[0] + bias.x), silu_f(v[1] + bias.y));
        p.y = pkbf(silu_f(v[2] + bias.z), silu_f(v[3] + bias.w));
        *reinterpret_cast<uint2*>(&h1b[nd][cb]) = p;
    }
    __syncthreads();

#pragma unroll
    for (int nt = 0; nt < 4; ++nt) acc[nt] = zero;
    for (int kt = 0; kt < 4; ++kt) {
        short8v b = *reinterpret_cast<const short8v*>(&h1b[(eh << 4) + r16][(kt << 5) + (g << 3)]);
#pragma unroll
        for (int nt = 0; nt < 4; ++nt) {
            short8v a = pv2[(((kt << 3) + (ch << 2) + nt) << 6) + l];
            acc[nt] = __builtin_amdgcn_mfma_f32_16x16x32_bf16(a, b, acc[nt], 0, 0, 0);
        }
    }
    {
        int gw = nb + (eh << 4) + r16;
        if (gw < N_NODES) {
#pragma unroll
            for (int nt = 0; nt < 4; ++nt) {
                int cb = (ch << 6) + (nt << 4) + (g << 2);
                float4 bias = *reinterpret_cast<const float4*>(&nb2[cb]);
                f32x4 v = acc[nt];
                float4 o;
                o.x = v[0] + bias.x; o.y = v[1] + bias.y;
                o.z = v[2] + bias.z; o.w = v[3] + bias.w;
                *reinterpret_cast<float4*>(&dout[(size_t)gw * HID + cb]) = o;
            }
        }
    }

    if (t < 96) {
        int nd = t / 3, d = t - 3 * nd;
        int gn = nb + nd;
        if (gn < N_NODES) {
            size_t xi = XOFF + (size_t)gn * 3 + d;
            float dg = deg[gn];
            dg = dg > 1.0f ? dg : 1.0f;
            dout[xi] = coord[(size_t)gn * 3 + d] + dout[xi] / dg;
        }
    }
}

extern "C" void kernel_launch(void* const* d_in, const int* in_sizes, int n_in,
                              void* d_out, int out_size, void* d_ws, size_t ws_size,
                              hipStream_t stream) {
    const float* node_feat = (const float*)d_in[0];
    const float* coord     = (const float*)d_in[1];
    const float* edge_feat = (const float*)d_in[2];
    const int*   src       = (const int*)d_in[3];
    const int*   dst       = (const int*)d_in[4];
    const float* eW1 = (const float*)d_in[5];
    const float* eb1 = (const float*)d_in[6];
    const float* eW2 = (const float*)d_in[7];
    const float* eb2 = (const float*)d_in[8];
    const float* nW1 = (const float*)d_in[9];
    const float* nb1 = (const float*)d_in[10];
    const float* nW2 = (const float*)d_in[11];
    const float* nb2 = (const float*)d_in[12];
    const float* cW1 = (const float*)d_in[13];
    const float* cb1 = (const float*)d_in[14];
    const float* cW2 = (const float*)d_in[15];

    float* out = (float*)d_out;
    float* deg = (float*)d_ws;
    char* base = (char*)d_ws;
    ushort* pk1  = (ushort*)(base + 200000);
    ushort* pk2  = (ushort*)(base + 273728);
    ushort* pk3  = (ushort*)(base + 306496);
    ushort* pkn1 = (ushort*)(base + 339264);
    ushort* pkn2 = (ushort*)(base + 404800);
    ushort* nfb  = (ushort*)(base + 437568);
    const size_t need_nfb = 437568 + (size_t)N_NODES * 128 * 2;
    const bool use_nfb = ws_size >= need_nfb;

    hipMemsetAsync(d_out, 0, (size_t)out_size * sizeof(float), stream);
    hipMemsetAsync(d_ws, 0, 200000, stream);

    int prep_grid = use_nfb ? (14848 + N_NODES * 16 + 255) / 256 : 58;
    prep_kernel<<<prep_grid, 256, 0, stream>>>(
        eW1, eW2, cW1, nW1, nW2, node_feat,
        pk1, pk2, pk3, pkn1, pkn2, nfb, use_nfb ? 1 : 0);

    if (use_nfb) {
        edge_kernel<true><<<E_TOTAL / EPB, 512, 0, stream>>>(
            node_feat, nfb, coord, edge_feat, src, dst,
            pk1, pk2, pk3, eb1, eb2, cb1, cW2, out, out + XOFF, deg);
        node_kernel<true><<<(N_NODES + 31) / 32, 256, 0, stream>>>(
            node_feat, nfb, coord, pkn1, pkn2, nb1, nb2, out, deg);
    } else {
        edge_kernel<false><<<E_TOTAL / EPB, 512, 0, stream>>>(
            node_feat, nfb, coord, edge_feat, src, dst,
            pk1, pk2, pk3, eb1, eb2, cb1, cW2, out, out + XOFF, deg);
        node_kernel<false><<<(N_NODES + 31) / 32, 256, 0, stream>>>(
            node_feat, nfb, coord, pkn1, pkn2, nb1, nb2, out, deg);
    }
}

// Round 5
// 551.842 us; speedup vs baseline: 2.8413x; 1.0056x over previous
//
#include <hip/hip_runtime.h>
#include <hip/hip_bf16.h>

#define N_NODES 50000
#define E_TOTAL 800000
#define IN      128
#define HID     128
#define EPB     64
#define XOFF    ((size_t)N_NODES * HID)
#define FP      296     // fbuf pitch (ushort); h1 folded in at col 160
#define H1OFF   160
#define HP      136     // node h1 pitch
#define CP      264     // node cat pitch

typedef __attribute__((ext_vector_type(8))) short short8v;
typedef __attribute__((ext_vector_type(4))) float f32x4;

__device__ __forceinline__ float silu_f(float x) { return x / (1.0f + __expf(-x)); }

__device__ __forceinline__ uint pkbf(float lo, float hi) {
    float2 f; f.x = lo; f.y = hi;
    __hip_bfloat162 h = __float22bfloat162_rn(f);
    union { __hip_bfloat162 h; uint u; } c; c.h = h;
    return c.u;
}

__device__ __forceinline__ ushort f2bf(float x) {
    uint u = __float_as_uint(x);
    u += 0x7fff + ((u >> 16) & 1);
    return (ushort)(u >> 16);
}

// ---------------------------------------------------------------------------
// prep: pack 5 weight matrices into MFMA fragment order (entry (kt,n,l)[j] =
// W[kt*32 + 8*(l>>4)+j][n*16 + (l&15)]) and convert node_feat->bf16.
// ---------------------------------------------------------------------------
__global__ __launch_bounds__(256) void prep_kernel(
    const float* __restrict__ eW1, const float* __restrict__ eW2,
    const float* __restrict__ cW1, const float* __restrict__ nW1,
    const float* __restrict__ nW2, const float* __restrict__ node_feat,
    ushort* __restrict__ pk1, ushort* __restrict__ pk2, ushort* __restrict__ pk3,
    ushort* __restrict__ pkn1, ushort* __restrict__ pkn2,
    ushort* __restrict__ nfb, int do_nfb)
{
    int id = blockIdx.x * 256 + threadIdx.x;
    if (id < 14848) {
        const float* W; ushort* dp; int K, idx;
        if (id < 4608)       { idx = id;         W = eW1; dp = pk1;  K = 259; }
        else if (id < 6656)  { idx = id - 4608;  W = eW2; dp = pk2;  K = 128; }
        else if (id < 8704)  { idx = id - 6656;  W = cW1; dp = pk3;  K = 128; }
        else if (id < 12800) { idx = id - 8704;  W = nW1; dp = pkn1; K = 256; }
        else                 { idx = id - 12800; W = nW2; dp = pkn2; K = 128; }
        int kt = idx >> 9, n = (idx >> 6) & 7, ll = idx & 63;
        int col = (n << 4) + (ll & 15);
        short8v o;
#pragma unroll
        for (int j = 0; j < 8; ++j) {
            int k = (kt << 5) + ((ll >> 4) << 3) + j;
            o[j] = (k < K) ? (short)f2bf(W[(size_t)k * 128 + col]) : (short)0;
        }
        *reinterpret_cast<short8v*>(dp + (size_t)idx * 8) = o;
    } else if (do_nfb) {
        int idx = id - 14848;
        if (idx < N_NODES * 16) {
            const float4* s = reinterpret_cast<const float4*>(node_feat + (size_t)idx * 8);
            float4 a = s[0], b = s[1];
            uint4 u;
            u.x = pkbf(a.x, a.y); u.y = pkbf(a.z, a.w);
            u.z = pkbf(b.x, b.y); u.w = pkbf(b.z, b.w);
            *reinterpret_cast<uint4*>(nfb + (size_t)idx * 8) = u;
        }
    }
}

// ---------------------------------------------------------------------------
// Edge kernel: 512 thr = 8 waves, EPB=64, 4 blocks/CU (LDS 40448 B).
// Wave w: ch=w&3 -> 32 channels, eh=w>>2 -> 32 edges.
// MFMA swapped: A=weight frag, B=feature frag -> C[row=chan, col=edge].
// h1 folded into fbuf cols [160..287]; msg into cols [0..127].
// ---------------------------------------------------------------------------
template<bool NFB>
__global__ __launch_bounds__(512, 8) void edge_kernel(
    const float* __restrict__ node_feat, const ushort* __restrict__ nfb,
    const float* __restrict__ coord, const float* __restrict__ edge_feat,
    const int* __restrict__ src, const int* __restrict__ dst,
    const ushort* __restrict__ pk1, const ushort* __restrict__ pk2,
    const ushort* __restrict__ pk3,
    const float* __restrict__ eb1, const float* __restrict__ eb2,
    const float* __restrict__ cb1, const float* __restrict__ cW2,
    float* __restrict__ hacc, float* __restrict__ xacc, float* __restrict__ deg)
{
    __shared__ __attribute__((aligned(16))) ushort fbuf[EPB][FP];
    __shared__ int   sbuf[EPB], dbuf[EPB];
    __shared__ float xdbuf[EPB][4];
    __shared__ float pbuf[4][EPB];

    const int t   = threadIdx.x;
    const int l   = t & 63;
    const int w   = t >> 6;
    const int ch  = w & 3;
    const int eh  = w >> 2;
    const int r16 = l & 15;
    const int g   = l >> 4;
    const int e_base = blockIdx.x * EPB;

    if (t < EPB) { sbuf[t] = src[e_base + t]; dbuf[t] = dst[e_base + t]; }
    __syncthreads();

    // ---- gather f = [h_src | h_dst] ----
    {
        const int e = t >> 3;
        const int c = (t & 7) << 5;     // 0..224
        if (NFB) {
            const ushort* sp = (c < 128) ? nfb + (size_t)sbuf[e] * 128 + c
                                         : nfb + (size_t)dbuf[e] * 128 + (c - 128);
            const short8v* spv = reinterpret_cast<const short8v*>(sp);
#pragma unroll
            for (int i = 0; i < 4; ++i)
                *reinterpret_cast<short8v*>(&fbuf[e][c + (i << 3)]) = spv[i];
        } else {
            const float* sp = (c < 128) ? node_feat + (size_t)sbuf[e] * 128 + c
                                        : node_feat + (size_t)dbuf[e] * 128 + (c - 128);
            const float4* spv = reinterpret_cast<const float4*>(sp);
#pragma unroll
            for (int i = 0; i < 4; ++i) {
                float4 a = spv[2 * i], b = spv[2 * i + 1];
                uint4 u;
                u.x = pkbf(a.x, a.y); u.y = pkbf(a.z, a.w);
                u.z = pkbf(b.x, b.y); u.w = pkbf(b.z, b.w);
                *reinterpret_cast<uint4*>(&fbuf[e][c + (i << 3)]) = u;
            }
        }
    }
    if (t < EPB) {
        const int e = t, s = sbuf[e], d = dbuf[e];
        float dx = coord[(size_t)s*3+0] - coord[(size_t)d*3+0];
        float dy = coord[(size_t)s*3+1] - coord[(size_t)d*3+1];
        float dz = coord[(size_t)s*3+2] - coord[(size_t)d*3+2];
        float radial = dx*dx + dy*dy + dz*dz;
        float inv = 1.0f / (sqrtf(radial) + 1e-30f);
        fbuf[e][256] = f2bf(radial);
        fbuf[e][257] = f2bf(edge_feat[(size_t)(e_base + e)*2 + 0]);
        fbuf[e][258] = f2bf(edge_feat[(size_t)(e_base + e)*2 + 1]);
#pragma unroll
        for (int k = 259; k < 288; ++k) fbuf[e][k] = 0;
        xdbuf[e][0] = dx * inv; xdbuf[e][1] = dy * inv; xdbuf[e][2] = dz * inv;
    }
    __syncthreads();

    const f32x4 zero = {0.f, 0.f, 0.f, 0.f};
    const short8v* pkv1 = reinterpret_cast<const short8v*>(pk1);
    const short8v* pkv2 = reinterpret_cast<const short8v*>(pk2);
    const short8v* pkv3 = reinterpret_cast<const short8v*>(pk3);

    // ---- GEMM1: K=288 ----
    f32x4 acc[2][2];
    acc[0][0] = zero; acc[0][1] = zero; acc[1][0] = zero; acc[1][1] = zero;
    for (int kt = 0; kt < 9; ++kt) {
        short8v b0 = *reinterpret_cast<const short8v*>(&fbuf[(eh << 5) + r16][(kt << 5) + (g << 3)]);
        short8v b1 = *reinterpret_cast<const short8v*>(&fbuf[(eh << 5) + 16 + r16][(kt << 5) + (g << 3)]);
#pragma unroll
        for (int nt = 0; nt < 2; ++nt) {
            short8v a = pkv1[(((kt << 3) + (ch << 1) + nt) << 6) + l];
            acc[0][nt] = __builtin_amdgcn_mfma_f32_16x16x32_bf16(a, b0, acc[0][nt], 0, 0, 0);
            acc[1][nt] = __builtin_amdgcn_mfma_f32_16x16x32_bf16(a, b1, acc[1][nt], 0, 0, 0);
        }
    }
    __syncthreads();    // all waves done reading fbuf[.][160..287]
#pragma unroll
    for (int nt = 0; nt < 2; ++nt) {
        int cb = (ch << 5) + (nt << 4) + (g << 2);
        float4 bias = *reinterpret_cast<const float4*>(&eb1[cb]);
#pragma unroll
        for (int et = 0; et < 2; ++et) {
            int e = (eh << 5) + (et << 4) + r16;
            f32x4 v = acc[et][nt];
            uint2 p;
            p.x = pkbf(silu_f(v[0] + bias.x), silu_f(v[1] + bias.y));
            p.y = pkbf(silu_f(v[2] + bias.z), silu_f(v[3] + bias.w));
            *reinterpret_cast<uint2*>(&fbuf[e][H1OFF + cb]) = p;
        }
    }
    __syncthreads();

    // ---- GEMM2: K=128 (h1 at fbuf[.][160..287]) -> silu -> msg at [0..127] ----
    acc[0][0] = zero; acc[0][1] = zero; acc[1][0] = zero; acc[1][1] = zero;
    for (int kt = 0; kt < 4; ++kt) {
        short8v b0 = *reinterpret_cast<const short8v*>(&fbuf[(eh << 5) + r16][H1OFF + (kt << 5) + (g << 3)]);
        short8v b1 = *reinterpret_cast<const short8v*>(&fbuf[(eh << 5) + 16 + r16][H1OFF + (kt << 5) + (g << 3)]);
#pragma unroll
        for (int nt = 0; nt < 2; ++nt) {
            short8v a = pkv2[(((kt << 3) + (ch << 1) + nt) << 6) + l];
            acc[0][nt] = __builtin_amdgcn_mfma_f32_16x16x32_bf16(a, b0, acc[0][nt], 0, 0, 0);
            acc[1][nt] = __builtin_amdgcn_mfma_f32_16x16x32_bf16(a, b1, acc[1][nt], 0, 0, 0);
        }
    }
#pragma unroll
    for (int nt = 0; nt < 2; ++nt) {
        int cb = (ch << 5) + (nt << 4) + (g << 2);
        float4 bias = *reinterpret_cast<const float4*>(&eb2[cb]);
#pragma unroll
        for (int et = 0; et < 2; ++et) {
            int e = (eh << 5) + (et << 4) + r16;
            f32x4 v = acc[et][nt];
            uint2 p;
            p.x = pkbf(silu_f(v[0] + bias.x), silu_f(v[1] + bias.y));
            p.y = pkbf(silu_f(v[2] + bias.z), silu_f(v[3] + bias.w));
            *reinterpret_cast<uint2*>(&fbuf[e][cb]) = p;
        }
    }
    __syncthreads();

    // ---- scatter msg_h from LDS, coalesced: 16 lanes = one 64B line ----
    {
        const int se = t >> 4;            // 0..31
        const int sc = t & 15;
#pragma unroll
        for (int p = 0; p < 2; ++p) {
            int e = se + (p << 5);
            int gd = dbuf[e];
            float* dp = hacc + (size_t)gd * HID + sc;
#pragma unroll
            for (int i = 0; i < 8; ++i) {
                ushort us = fbuf[e][sc + (i << 4)];
                atomicAdd(dp + (i << 4), __uint_as_float((uint)us << 16));
            }
        }
    }

    // ---- GEMM3: K=128 -> silu -> dot cW2 ----
    acc[0][0] = zero; acc[0][1] = zero; acc[1][0] = zero; acc[1][1] = zero;
    for (int kt = 0; kt < 4; ++kt) {
        short8v b0 = *reinterpret_cast<const short8v*>(&fbuf[(eh << 5) + r16][(kt << 5) + (g << 3)]);
        short8v b1 = *reinterpret_cast<const short8v*>(&fbuf[(eh << 5) + 16 + r16][(kt << 5) + (g << 3)]);
#pragma unroll
        for (int nt = 0; nt < 2; ++nt) {
            short8v a = pkv3[(((kt << 3) + (ch << 1) + nt) << 6) + l];
            acc[0][nt] = __builtin_amdgcn_mfma_f32_16x16x32_bf16(a, b0, acc[0][nt], 0, 0, 0);
            acc[1][nt] = __builtin_amdgcn_mfma_f32_16x16x32_bf16(a, b1, acc[1][nt], 0, 0, 0);
        }
    }
    float part[2] = {0.f, 0.f};
#pragma unroll
    for (int nt = 0; nt < 2; ++nt) {
        int cb = (ch << 5) + (nt << 4) + (g << 2);
        float4 bias = *reinterpret_cast<const float4*>(&cb1[cb]);
        float4 cw   = *reinterpret_cast<const float4*>(&cW2[cb]);
#pragma unroll
        for (int et = 0; et < 2; ++et) {
            f32x4 v = acc[et][nt];
            part[et] += silu_f(v[0] + bias.x) * cw.x + silu_f(v[1] + bias.y) * cw.y
                      + silu_f(v[2] + bias.z) * cw.z + silu_f(v[3] + bias.w) * cw.w;
        }
    }
#pragma unroll
    for (int et = 0; et < 2; ++et) {
        part[et] += __shfl_xor(part[et], 16);
        part[et] += __shfl_xor(part[et], 32);
    }
    if (l < 16) {
        pbuf[ch][(eh << 5) + r16]      = part[0];
        pbuf[ch][(eh << 5) + 16 + r16] = part[1];
    }
    __syncthreads();

    if (t < EPB) {
        float s = pbuf[0][t] + pbuf[1][t] + pbuf[2][t] + pbuf[3][t];
        int gd = dbuf[t];
        atomicAdd(&xacc[(size_t)gd*3 + 0], s * xdbuf[t][0]);
        atomicAdd(&xacc[(size_t)gd*3 + 1], s * xdbuf[t][1]);
        atomicAdd(&xacc[(size_t)gd*3 + 2], s * xdbuf[t][2]);
        atomicAdd(&deg[gd], 1.0f);
    }
}

// ---------------------------------------------------------------------------
// Node kernel (MFMA): 256 thr = 4 waves, 32 nodes/block.
// ---------------------------------------------------------------------------
template<bool NFB>
__global__ __launch_bounds__(256) void node_kernel(
    const float* __restrict__ node_feat, const ushort* __restrict__ nfb,
    const float* __restrict__ coord,
    const ushort* __restrict__ pkn1, const ushort* __restrict__ pkn2,
    const float* __restrict__ nb1, const float* __restrict__ nb2,
    float* __restrict__ dout, const float* __restrict__ deg)
{
    __shared__ __attribute__((aligned(16))) ushort catb[32][CP];
    __shared__ __attribute__((aligned(16))) ushort h1b[32][HP];

    const int t   = threadIdx.x;
    const int l   = t & 63;
    const int w   = t >> 6;
    const int ch  = w & 1;
    const int eh  = w >> 1;
    const int r16 = l & 15;
    const int g   = l >> 4;
    const int nb  = blockIdx.x * 32;

    {
        int nd = t >> 3;
        int c  = (t & 7) << 5;
        int gn = nb + nd; if (gn >= N_NODES) gn = N_NODES - 1;
        if (c < 128) {
            if (NFB) {
                const short8v* spv = reinterpret_cast<const short8v*>(nfb + (size_t)gn * 128 + c);
#pragma unroll
                for (int i = 0; i < 4; ++i)
                    *reinterpret_cast<short8v*>(&catb[nd][c + (i << 3)]) = spv[i];
            } else {
                const float4* spv = reinterpret_cast<const float4*>(node_feat + (size_t)gn * 128 + c);
#pragma unroll
                for (int i = 0; i < 4; ++i) {
                    float4 a = spv[2 * i], b = spv[2 * i + 1];
                    uint4 u;
                    u.x = pkbf(a.x, a.y); u.y = pkbf(a.z, a.w);
                    u.z = pkbf(b.x, b.y); u.w = pkbf(b.z, b.w);
                    *reinterpret_cast<uint4*>(&catb[nd][c + (i << 3)]) = u;
                }
            }
        } else {
            const float4* spv = reinterpret_cast<const float4*>(dout + (size_t)gn * HID + (c - 128));
#pragma unroll
            for (int i = 0; i < 4; ++i) {
                float4 a = spv[2 * i], b = spv[2 * i + 1];
                uint4 u;
                u.x = pkbf(a.x, a.y); u.y = pkbf(a.z, a.w);
                u.z = pkbf(b.x, b.y); u.w = pkbf(b.z, b.w);
                *reinterpret_cast<uint4*>(&catb[nd][c + (i << 3)]) = u;
            }
        }
    }
    __syncthreads();

    const f32x4 zero = {0.f, 0.f, 0.f, 0.f};
    const short8v* pv1 = reinterpret_cast<const short8v*>(pkn1);
    const short8v* pv2 = reinterpret_cast<const short8v*>(pkn2);

    f32x4 acc[4];
#pragma unroll
    for (int nt = 0; nt < 4; ++nt) acc[nt] = zero;
    for (int kt = 0; kt < 8; ++kt) {
        short8v b = *reinterpret_cast<const short8v*>(&catb[(eh << 4) + r16][(kt << 5) + (g << 3)]);
#pragma unroll
        for (int nt = 0; nt < 4; ++nt) {
            short8v a = pv1[(((kt << 3) + (ch << 2) + nt) << 6) + l];
            acc[nt] = __builtin_amdgcn_mfma_f32_16x16x32_bf16(a, b, acc[nt], 0, 0, 0);
        }
    }
#pragma unroll
    for (int nt = 0; nt < 4; ++nt) {
        int cb = (ch << 6) + (nt << 4) + (g << 2);
        float4 bias = *reinterpret_cast<const float4*>(&nb1[cb]);
        int nd = (eh << 4) + r16;
        f32x4 v = acc[nt];
        uint2 p;
        p.x = pkbf(silu_f(v[0] + bias.x), silu_f(v[1] + bias.y));
        p.y = pkbf(silu_f(v[2] + bias.z), silu_f(v[3] + bias.w));
        *reinterpret_cast<uint2*>(&h1b[nd][cb]) = p;
    }
    __syncthreads();

#pragma unroll
    for (int nt = 0; nt < 4; ++nt) acc[nt] = zero;
    for (int kt = 0; kt < 4; ++kt) {
        short8v b = *reinterpret_cast<const short8v*>(&h1b[(eh << 4) + r16][(kt << 5) + (g << 3)]);
#pragma unroll
        for (int nt = 0; nt < 4; ++nt) {
            short8v a = pv2[(((kt << 3) + (ch << 2) + nt) << 6) + l];
            acc[nt] = __builtin_amdgcn_mfma_f32_16x16x32_bf16(a, b, acc[nt], 0, 0, 0);
        }
    }
    {
        int gw = nb + (eh << 4) + r16;
        if (gw < N_NODES) {
#pragma unroll
            for (int nt = 0; nt < 4; ++nt) {
                int cb = (ch << 6) + (nt << 4) + (g << 2);
                float4 bias = *reinterpret_cast<const float4*>(&nb2[cb]);
                f32x4 v = acc[nt];
                float4 o;
                o.x = v[0] + bias.x; o.y = v[1] + bias.y;
                o.z = v[2] + bias.z; o.w = v[3] + bias.w;
                *reinterpret_cast<float4*>(&dout[(size_t)gw * HID + cb]) = o;
            }
        }
    }

    if (t < 96) {
        int nd = t / 3, d = t - 3 * nd;
        int gn = nb + nd;
        if (gn < N_NODES) {
            size_t xi = XOFF + (size_t)gn * 3 + d;
            float dg = deg[gn];
            dg = dg > 1.0f ? dg : 1.0f;
            dout[xi] = coord[(size_t)gn * 3 + d] + dout[xi] / dg;
        }
    }
}

extern "C" void kernel_launch(void* const* d_in, const int* in_sizes, int n_in,
                              void* d_out, int out_size, void* d_ws, size_t ws_size,
                              hipStream_t stream) {
    const float* node_feat = (const float*)d_in[0];
    const float* coord     = (const float*)d_in[1];
    const float* edge_feat = (const float*)d_in[2];
    const int*   src       = (const int*)d_in[3];
    const int*   dst       = (const int*)d_in[4];
    const float* eW1 = (const float*)d_in[5];
    const float* eb1 = (const float*)d_in[6];
    const float* eW2 = (const float*)d_in[7];
    const float* eb2 = (const float*)d_in[8];
    const float* nW1 = (const float*)d_in[9];
    const float* nb1 = (const float*)d_in[10];
    const float* nW2 = (const float*)d_in[11];
    const float* nb2 = (const float*)d_in[12];
    const float* cW1 = (const float*)d_in[13];
    const float* cb1 = (const float*)d_in[14];
    const float* cW2 = (const float*)d_in[15];

    float* out = (float*)d_out;
    float* deg = (float*)d_ws;
    char* base = (char*)d_ws;
    ushort* pk1  = (ushort*)(base + 200000);
    ushort* pk2  = (ushort*)(base + 273728);
    ushort* pk3  = (ushort*)(base + 306496);
    ushort* pkn1 = (ushort*)(base + 339264);
    ushort* pkn2 = (ushort*)(base + 404800);
    ushort* nfb  = (ushort*)(base + 437568);
    const size_t need_nfb = 437568 + (size_t)N_NODES * 128 * 2;
    const bool use_nfb = ws_size >= need_nfb;

    hipMemsetAsync(d_out, 0, (size_t)out_size * sizeof(float), stream);
    hipMemsetAsync(d_ws, 0, 200000, stream);

    int prep_grid = use_nfb ? (14848 + N_NODES * 16 + 255) / 256 : 58;
    prep_kernel<<<prep_grid, 256, 0, stream>>>(
        eW1, eW2, cW1, nW1, nW2, node_feat,
        pk1, pk2, pk3, pkn1, pkn2, nfb, use_nfb ? 1 : 0);

    if (use_nfb) {
        edge_kernel<true><<<E_TOTAL / EPB, 512, 0, stream>>>(
            node_feat, nfb, coord, edge_feat, src, dst,
            pk1, pk2, pk3, eb1, eb2, cb1, cW2, out, out + XOFF, deg);
        node_kernel<true><<<(N_NODES + 31) / 32, 256, 0, stream>>>(
            node_feat, nfb, coord, pkn1, pkn2, nb1, nb2, out, deg);
    } else {
        edge_kernel<false><<<E_TOTAL / EPB, 512, 0, stream>>>(
            node_feat, nfb, coord, edge_feat, src, dst,
            pk1, pk2, pk3, eb1, eb2, cb1, cW2, out, out + XOFF, deg);
        node_kernel<false><<<(N_NODES + 31) / 32, 256, 0, stream>>>(
            node_feat, nfb, coord, pkn1, pkn2, nb1, nb2, out, deg);
    }
}